// Round 3
// baseline (1205.011 us; speedup 1.0000x reference)
//
#include <hip/hip_runtime.h>
#include <hip/hip_bf16.h>
#include <math.h>

#define E_    1024
#define H_    16
#define DH_   64
#define FF_   4096
#define S_    2048
#define NB_   4
#define NTOK_ 8192   // NB_*S_

typedef float          f32x4_t  __attribute__((ext_vector_type(4)));
typedef unsigned short u16x8_t  __attribute__((ext_vector_type(8)));
typedef unsigned short u16x4_t  __attribute__((ext_vector_type(4)));
typedef __bf16         bf16x8_t __attribute__((ext_vector_type(8)));

#define BC8(x) __builtin_bit_cast(bf16x8_t, (x))

// round-to-nearest-even fp32 -> bf16 (finite inputs)
static __device__ __forceinline__ unsigned short f2bf(float f) {
  unsigned u = __float_as_uint(f);
  return (unsigned short)((u + 0x7FFF + ((u >> 16) & 1)) >> 16);
}
static __device__ __forceinline__ float bf2f(unsigned short h) {
  return __uint_as_float(((unsigned)h) << 16);
}

// ---------------------------------------------------------------------------
// Weight preprocessing: W [K][N] fp32 -> Th,Tl [N][K] bf16 (hi + residual-lo).
// ---------------------------------------------------------------------------
__global__ __launch_bounds__(256)
void transpose_split_k(const float* __restrict__ W,
                       unsigned short* __restrict__ Th,
                       unsigned short* __restrict__ Tl, int K, int N)
{
  __shared__ float tile[64][65];
  const int t  = threadIdx.x;
  const int n0 = blockIdx.x * 64;
  const int k0 = blockIdx.y * 64;
#pragma unroll
  for (int i = 0; i < 4; ++i) {
    const int idx = t + 256 * i;
    const int r  = idx >> 4;
    const int c4 = (idx & 15) * 4;
    const float4 v = *(const float4*)&W[(size_t)(k0 + r) * N + n0 + c4];
    tile[r][c4 + 0] = v.x; tile[r][c4 + 1] = v.y;
    tile[r][c4 + 2] = v.z; tile[r][c4 + 3] = v.w;
  }
  __syncthreads();
#pragma unroll
  for (int i = 0; i < 4; ++i) {
    const int idx = t + 256 * i;
    const int rr  = idx >> 4;        // output row (n)
    const int c4  = (idx & 15) * 4;  // output col (k)
    u16x4_t hv, lv;
#pragma unroll
    for (int j = 0; j < 4; ++j) {
      const float f = tile[c4 + j][rr];
      const unsigned short h = f2bf(f);
      hv[j] = h;
      lv[j] = f2bf(f - bf2f(h));
    }
    const size_t o = (size_t)(n0 + rr) * K + k0 + c4;
    *(u16x4_t*)&Th[o] = hv;
    *(u16x4_t*)&Tl[o] = lv;
  }
}

// ---------------------------------------------------------------------------
// bf16x3 split GEMM: C[M][N] = A[M][K](fp32) @ W + bias (+ReLU).
// acc += Ah*Wh + Ah*Wl + Al*Wh  (fp32 MFMA accumulate; lo*lo dropped ~2^-18).
// 128x128 tile, BK=32, 4 waves 2x2, 4x4 frags of 16x16x32_bf16.
// ---------------------------------------------------------------------------
template<int RELU>
__global__ __launch_bounds__(256)
void gemm_b3_k(const float* __restrict__ A,
               const unsigned short* __restrict__ Th,
               const unsigned short* __restrict__ Tl,
               const float* __restrict__ bias, float* __restrict__ C,
               int M, int N, int K)
{
  __shared__ __align__(16) unsigned short Ah[128][40];
  __shared__ __align__(16) unsigned short Al[128][40];
  __shared__ __align__(16) unsigned short Bh[128][40];
  __shared__ __align__(16) unsigned short Bl[128][40];
  const int t    = threadIdx.x;
  const int bm   = blockIdx.y * 128;
  const int bn   = blockIdx.x * 128;
  const int row  = t >> 1;
  const int seg  = t & 1;
  const int lane = t & 63;
  const int wid  = t >> 6;
  const int wr   = wid >> 1;
  const int wc   = wid & 1;
  const int fr   = lane & 15;
  const int fg   = lane >> 4;

  f32x4_t acc[4][4];
#pragma unroll
  for (int m = 0; m < 4; ++m)
#pragma unroll
    for (int n = 0; n < 4; ++n)
#pragma unroll
      for (int j = 0; j < 4; ++j) acc[m][n][j] = 0.0f;

  const float*          ag  = A  + (size_t)(bm + row) * K + seg * 16;
  const unsigned short* bhg = Th + (size_t)(bn + row) * K + seg * 16;
  const unsigned short* blg = Tl + (size_t)(bn + row) * K + seg * 16;

  for (int k0 = 0; k0 < K; k0 += 32) {
    const float4 av0 = *(const float4*)(ag + k0);
    const float4 av1 = *(const float4*)(ag + k0 + 4);
    const float4 av2 = *(const float4*)(ag + k0 + 8);
    const float4 av3 = *(const float4*)(ag + k0 + 12);
    const u16x8_t bh0 = *(const u16x8_t*)(bhg + k0);
    const u16x8_t bh1 = *(const u16x8_t*)(bhg + k0 + 8);
    const u16x8_t bl0 = *(const u16x8_t*)(blg + k0);
    const u16x8_t bl1 = *(const u16x8_t*)(blg + k0 + 8);
    const float f[16] = {av0.x,av0.y,av0.z,av0.w, av1.x,av1.y,av1.z,av1.w,
                         av2.x,av2.y,av2.z,av2.w, av3.x,av3.y,av3.z,av3.w};
    u16x8_t Hv[2], Lv[2];
#pragma unroll
    for (int i = 0; i < 16; ++i) {
      const unsigned short h = f2bf(f[i]);
      Hv[i >> 3][i & 7] = h;
      Lv[i >> 3][i & 7] = f2bf(f[i] - bf2f(h));
    }
    __syncthreads();
    *(u16x8_t*)&Ah[row][seg * 16]     = Hv[0];
    *(u16x8_t*)&Ah[row][seg * 16 + 8] = Hv[1];
    *(u16x8_t*)&Al[row][seg * 16]     = Lv[0];
    *(u16x8_t*)&Al[row][seg * 16 + 8] = Lv[1];
    *(u16x8_t*)&Bh[row][seg * 16]     = bh0;
    *(u16x8_t*)&Bh[row][seg * 16 + 8] = bh1;
    *(u16x8_t*)&Bl[row][seg * 16]     = bl0;
    *(u16x8_t*)&Bl[row][seg * 16 + 8] = bl1;
    __syncthreads();
    u16x8_t aH[4], aL[4], bH[4], bL[4];
#pragma unroll
    for (int m = 0; m < 4; ++m) {
      aH[m] = *(const u16x8_t*)&Ah[wr * 64 + m * 16 + fr][fg * 8];
      aL[m] = *(const u16x8_t*)&Al[wr * 64 + m * 16 + fr][fg * 8];
    }
#pragma unroll
    for (int n = 0; n < 4; ++n) {
      bH[n] = *(const u16x8_t*)&Bh[wc * 64 + n * 16 + fr][fg * 8];
      bL[n] = *(const u16x8_t*)&Bl[wc * 64 + n * 16 + fr][fg * 8];
    }
#pragma unroll
    for (int m = 0; m < 4; ++m)
#pragma unroll
      for (int n = 0; n < 4; ++n) {
        acc[m][n] = __builtin_amdgcn_mfma_f32_16x16x32_bf16(BC8(aL[m]), BC8(bH[n]), acc[m][n], 0, 0, 0);
        acc[m][n] = __builtin_amdgcn_mfma_f32_16x16x32_bf16(BC8(aH[m]), BC8(bL[n]), acc[m][n], 0, 0, 0);
        acc[m][n] = __builtin_amdgcn_mfma_f32_16x16x32_bf16(BC8(aH[m]), BC8(bH[n]), acc[m][n], 0, 0, 0);
      }
  }

#pragma unroll
  for (int n = 0; n < 4; ++n) {
    const int col = bn + wc * 64 + n * 16 + fr;
    const float bv = bias[col];
#pragma unroll
    for (int m = 0; m < 4; ++m) {
#pragma unroll
      for (int j = 0; j < 4; ++j) {
        float v = acc[m][n][j] + bv;
        if (RELU) v = fmaxf(v, 0.0f);
        C[(size_t)(bm + wr * 64 + m * 16 + fg * 4 + j) * N + col] = v;
      }
    }
  }
}

// ---------------------------------------------------------------------------
// MFMA flash attention (bf16 inputs, fp32 accumulate).
// Block = (n, h, 128-row Q tile), 4 waves x 32 q-rows. K-tiles of 64 keys.
// Frag-read layouts all contiguous 16B:
//   Qs [q][72]  row-major  (A of QK^T)
//   Ks [key][72] row-major (B of QK^T: col=key, k=d contiguous)
//   Vt [d][72]  TRANSPOSED (B of PV:   col=d,   k=key contiguous)
//   Ps [q][72]  row-major  (A of PV), written scalar in C/D layout
// ---------------------------------------------------------------------------
__global__ __launch_bounds__(256)
void attn_mfma_k(const float* __restrict__ Qg, const float* __restrict__ Kg,
                 const float* __restrict__ Vg, float* __restrict__ Og)
{
  __shared__ __align__(16) unsigned short Qs[128][72];
  __shared__ __align__(16) unsigned short Ks[64][72];
  __shared__ __align__(16) unsigned short Vt[64][72];
  __shared__ __align__(16) unsigned short Ps[128][72];

  const int t    = threadIdx.x;
  const int qt   = blockIdx.x;    // 0..15
  const int h    = blockIdx.y;
  const int n    = blockIdx.z;
  const int lane = t & 63;
  const int wid  = t >> 6;        // wave: owns q rows [wid*32, wid*32+32)
  const int fr   = lane & 15;
  const int hi   = lane >> 4;     // 0..3
  const size_t base = (size_t)n * S_ * E_ + (size_t)h * DH_;

  // ---- stage Q tile (128 x 64) as bf16, row-major ----
#pragma unroll
  for (int i = 0; i < 8; ++i) {
    const int idx = t + 256 * i;        // 0..2047
    const int r   = idx >> 4;           // q row 0..127
    const int d4  = (idx & 15) * 4;
    const float4 q4 = *(const float4*)&Qg[base + (size_t)(qt * 128 + r) * E_ + d4];
    u16x4_t pk;
    pk[0] = f2bf(q4.x); pk[1] = f2bf(q4.y); pk[2] = f2bf(q4.z); pk[3] = f2bf(q4.w);
    *(u16x4_t*)&Qs[r][d4] = pk;
  }

  f32x4_t acc[2][4];                 // ctx frags: m over q, n over d
  float m_run[2][4], l_run[2][4];    // per (m-frag, j) row state
#pragma unroll
  for (int m = 0; m < 2; ++m)
#pragma unroll
    for (int j = 0; j < 4; ++j) {
      m_run[m][j] = -INFINITY; l_run[m][j] = 0.0f;
      acc[m][0][j] = 0.0f; acc[m][1][j] = 0.0f; acc[m][2][j] = 0.0f; acc[m][3][j] = 0.0f;
    }

  const float cs = 0.18033688011112042f;  // log2(e) / sqrt(64)

  for (int kt = 0; kt < S_ / 64; ++kt) {
    // ---- prefetch K,V tiles (64x64 fp32) to regs ----
    float4 kv[4], vv[4];
#pragma unroll
    for (int i = 0; i < 4; ++i) {
      const int idx = t + 256 * i;      // 0..1023
      const int r   = idx >> 4;         // key 0..63
      const int d4  = (idx & 15) * 4;
      kv[i] = *(const float4*)&Kg[base + (size_t)(kt * 64 + r) * E_ + d4];
      vv[i] = *(const float4*)&Vg[base + (size_t)(kt * 64 + r) * E_ + d4];
    }
    __syncthreads();   // prev iter's PV reads (and Q staging) complete
#pragma unroll
    for (int i = 0; i < 4; ++i) {
      const int idx = t + 256 * i;
      const int r   = idx >> 4;
      const int d4  = (idx & 15) * 4;
      u16x4_t pk;
      pk[0] = f2bf(kv[i].x); pk[1] = f2bf(kv[i].y); pk[2] = f2bf(kv[i].z); pk[3] = f2bf(kv[i].w);
      *(u16x4_t*)&Ks[r][d4] = pk;
      Vt[d4 + 0][r] = f2bf(vv[i].x);    // transposed scalar writes
      Vt[d4 + 1][r] = f2bf(vv[i].y);
      Vt[d4 + 2][r] = f2bf(vv[i].z);
      Vt[d4 + 3][r] = f2bf(vv[i].w);
    }
    __syncthreads();

    // ---- QK^T: s[2 m][4 n] frags, k = d (2 steps of 32) ----
    f32x4_t s[2][4];
#pragma unroll
    for (int m = 0; m < 2; ++m)
#pragma unroll
      for (int nn = 0; nn < 4; ++nn)
#pragma unroll
        for (int j = 0; j < 4; ++j) s[m][nn][j] = 0.0f;
#pragma unroll
    for (int kk = 0; kk < 2; ++kk) {
      u16x8_t aq[2], bk[4];
#pragma unroll
      for (int m = 0; m < 2; ++m)
        aq[m] = *(const u16x8_t*)&Qs[wid * 32 + m * 16 + fr][kk * 32 + hi * 8];
#pragma unroll
      for (int nn = 0; nn < 4; ++nn)
        bk[nn] = *(const u16x8_t*)&Ks[nn * 16 + fr][kk * 32 + hi * 8];
#pragma unroll
      for (int m = 0; m < 2; ++m)
#pragma unroll
        for (int nn = 0; nn < 4; ++nn)
          s[m][nn] = __builtin_amdgcn_mfma_f32_16x16x32_bf16(BC8(aq[m]), BC8(bk[nn]), s[m][nn], 0, 0, 0);
    }

    // ---- online softmax (rows lane-group-local; reduce over 16 lanes) ----
    float p[2][4][4];
#pragma unroll
    for (int m = 0; m < 2; ++m)
#pragma unroll
      for (int j = 0; j < 4; ++j) {
        float v0 = fmaxf(fmaxf(s[m][0][j], s[m][1][j]), fmaxf(s[m][2][j], s[m][3][j]));
        v0 *= cs;
        v0 = fmaxf(v0, __shfl_xor(v0, 1));
        v0 = fmaxf(v0, __shfl_xor(v0, 2));
        v0 = fmaxf(v0, __shfl_xor(v0, 4));
        v0 = fmaxf(v0, __shfl_xor(v0, 8));
        const float mn   = fmaxf(m_run[m][j], v0);
        const float corr = exp2f(m_run[m][j] - mn);   // first tile: exp2(-inf)=0
        float ps = 0.0f;
#pragma unroll
        for (int nn = 0; nn < 4; ++nn) {
          const float pv = exp2f(s[m][nn][j] * cs - mn);
          p[m][nn][j] = pv;
          ps += pv;
        }
        ps += __shfl_xor(ps, 1);
        ps += __shfl_xor(ps, 2);
        ps += __shfl_xor(ps, 4);
        ps += __shfl_xor(ps, 8);
        l_run[m][j] = l_run[m][j] * corr + ps;
        m_run[m][j] = mn;
#pragma unroll
        for (int nn = 0; nn < 4; ++nn) acc[m][nn][j] *= corr;
      }

    // ---- write P (C/D layout -> row-major Ps) ----
#pragma unroll
    for (int m = 0; m < 2; ++m)
#pragma unroll
      for (int nn = 0; nn < 4; ++nn)
#pragma unroll
        for (int j = 0; j < 4; ++j)
          Ps[wid * 32 + m * 16 + hi * 4 + j][nn * 16 + fr] = f2bf(p[m][nn][j]);
    __syncthreads();

    // ---- PV: acc[2 m][4 n] += P(32xk64) @ V(k64 x d64), k = key ----
#pragma unroll
    for (int kk = 0; kk < 2; ++kk) {
      u16x8_t ap[2], bv[4];
#pragma unroll
      for (int m = 0; m < 2; ++m)
        ap[m] = *(const u16x8_t*)&Ps[wid * 32 + m * 16 + fr][kk * 32 + hi * 8];
#pragma unroll
      for (int nn = 0; nn < 4; ++nn)
        bv[nn] = *(const u16x8_t*)&Vt[nn * 16 + fr][kk * 32 + hi * 8];
#pragma unroll
      for (int m = 0; m < 2; ++m)
#pragma unroll
        for (int nn = 0; nn < 4; ++nn)
          acc[m][nn] = __builtin_amdgcn_mfma_f32_16x16x32_bf16(BC8(ap[m]), BC8(bv[nn]), acc[m][nn], 0, 0, 0);
    }
  }

  // ---- epilogue: divide by l, store ctx (C/D layout: col=d, row=q) ----
#pragma unroll
  for (int m = 0; m < 2; ++m)
#pragma unroll
    for (int j = 0; j < 4; ++j) {
      const float inv = 1.0f / l_run[m][j];
      const size_t o = base + (size_t)(qt * 128 + wid * 32 + m * 16 + hi * 4 + j) * E_;
#pragma unroll
      for (int nn = 0; nn < 4; ++nn)
        Og[o + nn * 16 + fr] = acc[m][nn][j] * inv;
    }
}

// ---------------------------------------------------------------------------
// out = LayerNorm(A + B) * g + be   (one block per row, in-register)
// ---------------------------------------------------------------------------
__global__ __launch_bounds__(256)
void add_ln_k(const float* __restrict__ A, const float* __restrict__ B,
              const float* __restrict__ g, const float* __restrict__ be,
              float* __restrict__ out)
{
  __shared__ float red[8];
  const int row = blockIdx.x;
  const int t = threadIdx.x;
  const size_t off = (size_t)row * E_ + t * 4;
  const float4 a = *(const float4*)&A[off];
  const float4 b = *(const float4*)&B[off];
  float4 x;
  x.x = a.x + b.x; x.y = a.y + b.y; x.z = a.z + b.z; x.w = a.w + b.w;

  float s = x.x + x.y + x.z + x.w;
  s += __shfl_xor(s, 1);  s += __shfl_xor(s, 2);  s += __shfl_xor(s, 4);
  s += __shfl_xor(s, 8);  s += __shfl_xor(s, 16); s += __shfl_xor(s, 32);
  if ((t & 63) == 0) red[t >> 6] = s;
  __syncthreads();
  const float mu = (red[0] + red[1] + red[2] + red[3]) * (1.0f / E_);

  float4 xc;
  xc.x = x.x - mu; xc.y = x.y - mu; xc.z = x.z - mu; xc.w = x.w - mu;
  float q = xc.x*xc.x + xc.y*xc.y + xc.z*xc.z + xc.w*xc.w;
  q += __shfl_xor(q, 1);  q += __shfl_xor(q, 2);  q += __shfl_xor(q, 4);
  q += __shfl_xor(q, 8);  q += __shfl_xor(q, 16); q += __shfl_xor(q, 32);
  __syncthreads();
  if ((t & 63) == 0) red[4 + (t >> 6)] = q;
  __syncthreads();
  const float var = (red[4] + red[5] + red[6] + red[7]) * (1.0f / E_);
  const float inv = rsqrtf(var + 1e-5f);

  const float4 gg = *(const float4*)&g[t * 4];
  const float4 bb = *(const float4*)&be[t * 4];
  float4 o;
  o.x = xc.x * inv * gg.x + bb.x;
  o.y = xc.y * inv * gg.y + bb.y;
  o.z = xc.z * inv * gg.z + bb.z;
  o.w = xc.w * inv * gg.w + bb.w;
  *(float4*)&out[off] = o;
}

// ---------------------------------------------------------------------------
extern "C" void kernel_launch(void* const* d_in, const int* in_sizes, int n_in,
                              void* d_out, int out_size, void* d_ws, size_t ws_size,
                              hipStream_t stream)
{
  const float* x   = (const float*)d_in[0];
  const float* Wq  = (const float*)d_in[1];
  const float* bq  = (const float*)d_in[2];
  const float* Wk  = (const float*)d_in[3];
  const float* bk  = (const float*)d_in[4];
  const float* Wv  = (const float*)d_in[5];
  const float* bv  = (const float*)d_in[6];
  const float* Wo  = (const float*)d_in[7];
  const float* bo  = (const float*)d_in[8];
  const float* W1  = (const float*)d_in[9];
  const float* b1  = (const float*)d_in[10];
  const float* W2  = (const float*)d_in[11];
  const float* b2  = (const float*)d_in[12];
  const float* g1  = (const float*)d_in[13];
  const float* be1 = (const float*)d_in[14];
  const float* g2  = (const float*)d_in[15];
  const float* be2 = (const float*)d_in[16];
  float* out = (float*)d_out;
  float* ws  = (float*)d_ws;

  // fp32 activation workspace: 6*TE floats = 192 MiB
  const size_t TE = (size_t)NTOK_ * E_;     // 8388608
  float* Qb = ws;                           // later: mh, then ff1
  float* Kb = ws + TE;
  float* Vb = ws + 2 * TE;
  float* Cb = ws + 3 * TE;
  float* N1 = ws + 4 * TE;                  // persists
  float* F2 = ws + 5 * TE;
  float* F1 = ws;                           // 4*TE floats, overlaps dead Q/K/V/ctx
  float* Mh = Qb;                           // reuses Q (dead after attention)

  // bf16 weight splits after the fp32 region: 24M ushorts = 48 MiB (peak 240 MiB)
  unsigned short* wsp = (unsigned short*)(ws + 6 * TE);
  const size_t EE = (size_t)E_ * E_;        // 1M
  unsigned short* ThQ = wsp;            unsigned short* TlQ = wsp + EE;
  unsigned short* ThK = wsp + 2 * EE;   unsigned short* TlK = wsp + 3 * EE;
  unsigned short* ThV = wsp + 4 * EE;   unsigned short* TlV = wsp + 5 * EE;
  unsigned short* ThO = wsp + 6 * EE;   unsigned short* TlO = wsp + 7 * EE;
  unsigned short* Th1 = wsp + 8 * EE;   unsigned short* Tl1 = wsp + 12 * EE;  // E x FF
  unsigned short* Th2 = wsp + 16 * EE;  unsigned short* Tl2 = wsp + 20 * EE;  // FF x E

  dim3 blk(256);
  transpose_split_k<<<dim3(E_/64,  E_/64),  blk, 0, stream>>>(Wq, ThQ, TlQ, E_,  E_);
  transpose_split_k<<<dim3(E_/64,  E_/64),  blk, 0, stream>>>(Wk, ThK, TlK, E_,  E_);
  transpose_split_k<<<dim3(E_/64,  E_/64),  blk, 0, stream>>>(Wv, ThV, TlV, E_,  E_);
  transpose_split_k<<<dim3(E_/64,  E_/64),  blk, 0, stream>>>(Wo, ThO, TlO, E_,  E_);
  transpose_split_k<<<dim3(FF_/64, E_/64),  blk, 0, stream>>>(W1, Th1, Tl1, E_,  FF_);
  transpose_split_k<<<dim3(E_/64,  FF_/64), blk, 0, stream>>>(W2, Th2, Tl2, FF_, E_);

  dim3 ge(E_ / 128, NTOK_ / 128);           // (8, 64)
  dim3 gf(FF_ / 128, NTOK_ / 128);          // (32, 64)

  gemm_b3_k<0><<<ge, blk, 0, stream>>>(x,  ThQ, TlQ, bq, Qb, NTOK_, E_, E_);
  gemm_b3_k<0><<<ge, blk, 0, stream>>>(x,  ThK, TlK, bk, Kb, NTOK_, E_, E_);
  gemm_b3_k<0><<<ge, blk, 0, stream>>>(x,  ThV, TlV, bv, Vb, NTOK_, E_, E_);
  attn_mfma_k<<<dim3(S_ / 128, H_, NB_), blk, 0, stream>>>(Qb, Kb, Vb, Cb);
  gemm_b3_k<0><<<ge, blk, 0, stream>>>(Cb, ThO, TlO, bo, Mh, NTOK_, E_, E_);
  add_ln_k<<<dim3(NTOK_), blk, 0, stream>>>(Mh, x, g1, be1, N1);
  gemm_b3_k<1><<<gf, blk, 0, stream>>>(N1, Th1, Tl1, b1, F1, NTOK_, FF_, E_);
  gemm_b3_k<0><<<ge, blk, 0, stream>>>(F1, Th2, Tl2, b2, F2, NTOK_, E_, FF_);
  add_ln_k<<<dim3(NTOK_), blk, 0, stream>>>(F2, N1, g2, be2, out);
}

// Round 5
// 784.761 us; speedup vs baseline: 1.5355x; 1.5355x over previous
//
#include <hip/hip_runtime.h>
#include <hip/hip_bf16.h>
#include <math.h>

#define E_    1024
#define H_    16
#define DH_   64
#define FF_   4096
#define S_    2048
#define NB_   4
#define NTOK_ 8192   // NB_*S_

typedef float          f32x4_t  __attribute__((ext_vector_type(4)));
typedef unsigned short u16x8_t  __attribute__((ext_vector_type(8)));
typedef unsigned short u16x4_t  __attribute__((ext_vector_type(4)));
typedef __bf16         bf16x8_t __attribute__((ext_vector_type(8)));

#define BC8(x) __builtin_bit_cast(bf16x8_t, (x))

// round-to-nearest-even fp32 -> bf16 (finite inputs)
static __device__ __forceinline__ unsigned short f2bf(float f) {
  unsigned u = __float_as_uint(f);
  return (unsigned short)((u + 0x7FFF + ((u >> 16) & 1)) >> 16);
}

// ---------------------------------------------------------------------------
// fp32 -> bf16 bulk convert (exact grid: n = grid*256*4)
// ---------------------------------------------------------------------------
__global__ __launch_bounds__(256)
void cvt_bf16_k(const float* __restrict__ in, unsigned short* __restrict__ out)
{
  const size_t i = ((size_t)blockIdx.x * 256 + threadIdx.x) * 4;
  const float4 v = *(const float4*)&in[i];
  u16x4_t p;
  p[0] = f2bf(v.x); p[1] = f2bf(v.y); p[2] = f2bf(v.z); p[3] = f2bf(v.w);
  *(u16x4_t*)&out[i] = p;
}

// ---------------------------------------------------------------------------
// Weight preprocessing: W [K][N] fp32 -> Th [N][K] bf16 (transpose + round).
// ---------------------------------------------------------------------------
__global__ __launch_bounds__(256)
void transpose_bf16_k(const float* __restrict__ W,
                      unsigned short* __restrict__ Th, int K, int N)
{
  __shared__ float tile[64][65];
  const int t  = threadIdx.x;
  const int n0 = blockIdx.x * 64;
  const int k0 = blockIdx.y * 64;
#pragma unroll
  for (int i = 0; i < 4; ++i) {
    const int idx = t + 256 * i;
    const int r  = idx >> 4;
    const int c4 = (idx & 15) * 4;
    const float4 v = *(const float4*)&W[(size_t)(k0 + r) * N + n0 + c4];
    tile[r][c4 + 0] = v.x; tile[r][c4 + 1] = v.y;
    tile[r][c4 + 2] = v.z; tile[r][c4 + 3] = v.w;
  }
  __syncthreads();
#pragma unroll
  for (int i = 0; i < 4; ++i) {
    const int idx = t + 256 * i;
    const int rr  = idx >> 4;        // output row (n)
    const int c4  = (idx & 15) * 4;  // output col (k)
    u16x4_t hv;
#pragma unroll
    for (int j = 0; j < 4; ++j) hv[j] = f2bf(tile[c4 + j][rr]);
    *(u16x4_t*)&Th[(size_t)(n0 + rr) * K + k0 + c4] = hv;
  }
}

// ---------------------------------------------------------------------------
// Pure-bf16 GEMM: out = A[M][K](bf16) @ Th^T + bias (+ReLU).
// Th is [N][K] bf16. 128x128 tile, BK=32, 4 waves 2x2, 4x4 frags 16x16x32.
// MODE 0: fp32 row-major   MODE 1: bf16 row-major
// MODE 2: bf16 V^T layout [n][h][d][s] (for attention's PV B-operand)
// XCD-aware bijective block swizzle (nwg % 8 == 0 for all our grids).
// ---------------------------------------------------------------------------
template<int RELU, int MODE>
__global__ __launch_bounds__(256)
void gemm_bf16_k(const unsigned short* __restrict__ A,
                 const unsigned short* __restrict__ Th,
                 const float* __restrict__ bias, void* __restrict__ outp,
                 int M, int N, int K)
{
  __shared__ __align__(16) unsigned short Ah[128][40];
  __shared__ __align__(16) unsigned short Bh[128][40];
  const int t    = threadIdx.x;
  const int nwg  = gridDim.x * gridDim.y;
  int id = blockIdx.x + gridDim.x * blockIdx.y;
  id = (id & 7) * (nwg >> 3) + (id >> 3);       // chunk per XCD
  const int bn = (id % gridDim.x) * 128;
  const int bm = (id / gridDim.x) * 128;
  const int row  = t >> 1;        // staging row 0..127
  const int seg  = t & 1;         // 16-wide k segment
  const int lane = t & 63;
  const int wid  = t >> 6;
  const int wr   = wid >> 1;      // 2x2 wave grid, 64x64 per wave
  const int wc   = wid & 1;
  const int fr   = lane & 15;
  const int fg   = lane >> 4;

  f32x4_t acc[4][4];
#pragma unroll
  for (int m = 0; m < 4; ++m)
#pragma unroll
    for (int n = 0; n < 4; ++n)
#pragma unroll
      for (int j = 0; j < 4; ++j) acc[m][n][j] = 0.0f;

  const unsigned short* ag = A  + (size_t)(bm + row) * K + seg * 16;
  const unsigned short* bg = Th + (size_t)(bn + row) * K + seg * 16;

  for (int k0 = 0; k0 < K; k0 += 32) {
    const u16x8_t a0 = *(const u16x8_t*)(ag + k0);
    const u16x8_t a1 = *(const u16x8_t*)(ag + k0 + 8);
    const u16x8_t b0 = *(const u16x8_t*)(bg + k0);
    const u16x8_t b1 = *(const u16x8_t*)(bg + k0 + 8);
    __syncthreads();   // previous iteration's frag reads done
    *(u16x8_t*)&Ah[row][seg * 16]     = a0;
    *(u16x8_t*)&Ah[row][seg * 16 + 8] = a1;
    *(u16x8_t*)&Bh[row][seg * 16]     = b0;
    *(u16x8_t*)&Bh[row][seg * 16 + 8] = b1;
    __syncthreads();
    u16x8_t aH[4], bH[4];
#pragma unroll
    for (int m = 0; m < 4; ++m)
      aH[m] = *(const u16x8_t*)&Ah[wr * 64 + m * 16 + fr][fg * 8];
#pragma unroll
    for (int n = 0; n < 4; ++n)
      bH[n] = *(const u16x8_t*)&Bh[wc * 64 + n * 16 + fr][fg * 8];
#pragma unroll
    for (int m = 0; m < 4; ++m)
#pragma unroll
      for (int n = 0; n < 4; ++n)
        acc[m][n] = __builtin_amdgcn_mfma_f32_16x16x32_bf16(BC8(aH[m]), BC8(bH[n]), acc[m][n], 0, 0, 0);
  }

  // epilogue: C/D layout col=lane&15, row=(lane>>4)*4+reg
#pragma unroll
  for (int n = 0; n < 4; ++n) {
    const int col = bn + wc * 64 + n * 16 + fr;
    const float bv = bias[col];
#pragma unroll
    for (int m = 0; m < 4; ++m) {
      const int row0 = bm + wr * 64 + m * 16 + fg * 4;   // 4 consecutive rows
      if (MODE == 2) {
        // V^T: rows are tokens (n,s), cols are (h,d); write u16x4 along s
        const int nb = row0 >> 11;          // S_=2048
        const int s  = row0 & 2047;
        const int hh = col >> 6;            // DH_=64
        const int dd = col & 63;
        u16x4_t pk;
#pragma unroll
        for (int j = 0; j < 4; ++j) pk[j] = f2bf(acc[m][n][j] + bv);
        *(u16x4_t*)&((unsigned short*)outp)[((size_t)((nb * H_ + hh) * DH_ + dd)) * S_ + s] = pk;
      } else {
#pragma unroll
        for (int j = 0; j < 4; ++j) {
          float v = acc[m][n][j] + bv;
          if (RELU) v = fmaxf(v, 0.0f);
          const size_t o = (size_t)(row0 + j) * N + col;
          if (MODE == 0) ((float*)outp)[o] = v;
          else           ((unsigned short*)outp)[o] = f2bf(v);
        }
      }
    }
  }
}

// ---------------------------------------------------------------------------
// MFMA flash attention (bf16 in/out, fp32 softmax+accum).
// Block = (n, h, 128-row Q tile), 4 waves x 32 q-rows, K-tiles of 64 keys.
// V arrives PRE-TRANSPOSED in global ([n][h][d][s]) -> all LDS staging is
// row-major vector writes (no transposed scalar writes -> no 8-way conflicts).
// ---------------------------------------------------------------------------
__global__ __launch_bounds__(256)
void attn_mfma_k(const unsigned short* __restrict__ Qg,
                 const unsigned short* __restrict__ Kg,
                 const unsigned short* __restrict__ VTg,
                 unsigned short* __restrict__ Og)
{
  __shared__ __align__(16) unsigned short Qs[128][72];
  __shared__ __align__(16) unsigned short Ks[64][72];
  __shared__ __align__(16) unsigned short Vt[64][72];   // [d][key]
  __shared__ __align__(16) unsigned short Ps[128][72];

  const int t = threadIdx.x;
  // XCD swizzle: 16 consecutive id2 (same h,n; all qt) per L2 chunk
  const int nwg = gridDim.x * gridDim.y * gridDim.z;     // 1024
  int id = blockIdx.x + gridDim.x * (blockIdx.y + gridDim.y * blockIdx.z);
  id = (id & 7) * (nwg >> 3) + (id >> 3);
  const int qt = id & 15;
  const int h  = (id >> 4) & 15;
  const int n  = id >> 8;

  const int lane = t & 63;
  const int wid  = t >> 6;        // wave owns q rows [wid*32, +32)
  const int fr   = lane & 15;
  const int hi   = lane >> 4;     // 0..3
  const size_t baseq = (size_t)n * S_ * E_ + (size_t)h * DH_;
  const size_t basev = (size_t)(n * H_ + h) * DH_ * S_;

  // ---- stage Q tile (128 x 64) row-major, u16x8 ----
#pragma unroll
  for (int i = 0; i < 4; ++i) {
    const int idx = t + 256 * i;        // 0..1023
    const int r   = idx >> 3;           // 0..127
    const int c8  = (idx & 7) * 8;
    *(u16x8_t*)&Qs[r][c8] = *(const u16x8_t*)&Qg[baseq + (size_t)(qt * 128 + r) * E_ + c8];
  }

  f32x4_t acc[2][4];
  float m_run[2][4], l_run[2][4];
#pragma unroll
  for (int m = 0; m < 2; ++m)
#pragma unroll
    for (int j = 0; j < 4; ++j) {
      m_run[m][j] = -INFINITY; l_run[m][j] = 0.0f;
      acc[m][0][j] = 0.0f; acc[m][1][j] = 0.0f; acc[m][2][j] = 0.0f; acc[m][3][j] = 0.0f;
    }

  const float cs = 0.18033688011112042f;  // log2(e) / sqrt(64)

  for (int kt = 0; kt < S_ / 64; ++kt) {
    // ---- prefetch K (row-major) and V^T (row-major [d][key]) tiles ----
    u16x8_t kr[2], vr[2];
#pragma unroll
    for (int i = 0; i < 2; ++i) {
      const int idx = t + 256 * i;      // 0..511
      const int r   = idx >> 3;         // 0..63
      const int c8  = (idx & 7) * 8;
      kr[i] = *(const u16x8_t*)&Kg[baseq + (size_t)(kt * 64 + r) * E_ + c8];
      vr[i] = *(const u16x8_t*)&VTg[basev + (size_t)r * S_ + kt * 64 + c8];
    }
    __syncthreads();   // prev iter's frag reads done
#pragma unroll
    for (int i = 0; i < 2; ++i) {
      const int idx = t + 256 * i;
      const int r   = idx >> 3;
      const int c8  = (idx & 7) * 8;
      *(u16x8_t*)&Ks[r][c8] = kr[i];
      *(u16x8_t*)&Vt[r][c8] = vr[i];
    }
    __syncthreads();

    // ---- QK^T ----
    f32x4_t s[2][4];
#pragma unroll
    for (int m = 0; m < 2; ++m)
#pragma unroll
      for (int nn = 0; nn < 4; ++nn)
#pragma unroll
        for (int j = 0; j < 4; ++j) s[m][nn][j] = 0.0f;
#pragma unroll
    for (int kk = 0; kk < 2; ++kk) {
      u16x8_t aq[2], bk[4];
#pragma unroll
      for (int m = 0; m < 2; ++m)
        aq[m] = *(const u16x8_t*)&Qs[wid * 32 + m * 16 + fr][kk * 32 + hi * 8];
#pragma unroll
      for (int nn = 0; nn < 4; ++nn)
        bk[nn] = *(const u16x8_t*)&Ks[nn * 16 + fr][kk * 32 + hi * 8];
#pragma unroll
      for (int m = 0; m < 2; ++m)
#pragma unroll
        for (int nn = 0; nn < 4; ++nn)
          s[m][nn] = __builtin_amdgcn_mfma_f32_16x16x32_bf16(BC8(aq[m]), BC8(bk[nn]), s[m][nn], 0, 0, 0);
    }

    // ---- online softmax (rows lane-local per 16-lane group) ----
    float p[2][4][4];
#pragma unroll
    for (int m = 0; m < 2; ++m)
#pragma unroll
      for (int j = 0; j < 4; ++j) {
        float v0 = fmaxf(fmaxf(s[m][0][j], s[m][1][j]), fmaxf(s[m][2][j], s[m][3][j]));
        v0 *= cs;
        v0 = fmaxf(v0, __shfl_xor(v0, 1));
        v0 = fmaxf(v0, __shfl_xor(v0, 2));
        v0 = fmaxf(v0, __shfl_xor(v0, 4));
        v0 = fmaxf(v0, __shfl_xor(v0, 8));
        const float mn   = fmaxf(m_run[m][j], v0);
        const float corr = exp2f(m_run[m][j] - mn);
        float ps = 0.0f;
#pragma unroll
        for (int nn = 0; nn < 4; ++nn) {
          const float pv = exp2f(s[m][nn][j] * cs - mn);
          p[m][nn][j] = pv;
          ps += pv;
        }
        ps += __shfl_xor(ps, 1);
        ps += __shfl_xor(ps, 2);
        ps += __shfl_xor(ps, 4);
        ps += __shfl_xor(ps, 8);
        l_run[m][j] = l_run[m][j] * corr + ps;
        m_run[m][j] = mn;
#pragma unroll
        for (int nn = 0; nn < 4; ++nn) acc[m][nn][j] *= corr;
      }

    // ---- P to LDS (C/D layout -> row-major) ----
#pragma unroll
    for (int m = 0; m < 2; ++m)
#pragma unroll
      for (int nn = 0; nn < 4; ++nn)
#pragma unroll
        for (int j = 0; j < 4; ++j)
          Ps[wid * 32 + m * 16 + hi * 4 + j][nn * 16 + fr] = f2bf(p[m][nn][j]);
    __syncthreads();

    // ---- PV ----
#pragma unroll
    for (int kk = 0; kk < 2; ++kk) {
      u16x8_t ap[2], bv[4];
#pragma unroll
      for (int m = 0; m < 2; ++m)
        ap[m] = *(const u16x8_t*)&Ps[wid * 32 + m * 16 + fr][kk * 32 + hi * 8];
#pragma unroll
      for (int nn = 0; nn < 4; ++nn)
        bv[nn] = *(const u16x8_t*)&Vt[nn * 16 + fr][kk * 32 + hi * 8];
#pragma unroll
      for (int m = 0; m < 2; ++m)
#pragma unroll
        for (int nn = 0; nn < 4; ++nn)
          acc[m][nn] = __builtin_amdgcn_mfma_f32_16x16x32_bf16(BC8(ap[m]), BC8(bv[nn]), acc[m][nn], 0, 0, 0);
    }
  }

  // ---- epilogue: bf16 ctx out ----
#pragma unroll
  for (int m = 0; m < 2; ++m)
#pragma unroll
    for (int j = 0; j < 4; ++j) {
      const float inv = 1.0f / l_run[m][j];
      const size_t o = baseq + (size_t)(qt * 128 + wid * 32 + m * 16 + hi * 4 + j) * E_;
#pragma unroll
      for (int nn = 0; nn < 4; ++nn)
        Og[o + nn * 16 + fr] = f2bf(acc[m][nn][j] * inv);
    }
}

// ---------------------------------------------------------------------------
// out = LayerNorm(A + B) * g + be  (fp32 out; optional bf16 secondary out)
// ---------------------------------------------------------------------------
template<int WB16>
__global__ __launch_bounds__(256)
void add_ln_k(const float* __restrict__ A, const float* __restrict__ B,
              const float* __restrict__ g, const float* __restrict__ be,
              float* __restrict__ out, unsigned short* __restrict__ outb)
{
  __shared__ float red[8];
  const int row = blockIdx.x;
  const int t = threadIdx.x;
  const size_t off = (size_t)row * E_ + t * 4;
  const float4 a = *(const float4*)&A[off];
  const float4 b = *(const float4*)&B[off];
  float4 x;
  x.x = a.x + b.x; x.y = a.y + b.y; x.z = a.z + b.z; x.w = a.w + b.w;

  float s = x.x + x.y + x.z + x.w;
  s += __shfl_xor(s, 1);  s += __shfl_xor(s, 2);  s += __shfl_xor(s, 4);
  s += __shfl_xor(s, 8);  s += __shfl_xor(s, 16); s += __shfl_xor(s, 32);
  if ((t & 63) == 0) red[t >> 6] = s;
  __syncthreads();
  const float mu = (red[0] + red[1] + red[2] + red[3]) * (1.0f / E_);

  float4 xc;
  xc.x = x.x - mu; xc.y = x.y - mu; xc.z = x.z - mu; xc.w = x.w - mu;
  float q = xc.x*xc.x + xc.y*xc.y + xc.z*xc.z + xc.w*xc.w;
  q += __shfl_xor(q, 1);  q += __shfl_xor(q, 2);  q += __shfl_xor(q, 4);
  q += __shfl_xor(q, 8);  q += __shfl_xor(q, 16); q += __shfl_xor(q, 32);
  __syncthreads();
  if ((t & 63) == 0) red[4 + (t >> 6)] = q;
  __syncthreads();
  const float var = (red[4] + red[5] + red[6] + red[7]) * (1.0f / E_);
  const float inv = rsqrtf(var + 1e-5f);

  const float4 gg = *(const float4*)&g[t * 4];
  const float4 bb = *(const float4*)&be[t * 4];
  float4 o;
  o.x = xc.x * inv * gg.x + bb.x;
  o.y = xc.y * inv * gg.y + bb.y;
  o.z = xc.z * inv * gg.z + bb.z;
  o.w = xc.w * inv * gg.w + bb.w;
  *(float4*)&out[off] = o;
  if (WB16) {
    u16x4_t p;
    p[0] = f2bf(o.x); p[1] = f2bf(o.y); p[2] = f2bf(o.z); p[3] = f2bf(o.w);
    *(u16x4_t*)&outb[off] = p;
  }
}

// ---------------------------------------------------------------------------
extern "C" void kernel_launch(void* const* d_in, const int* in_sizes, int n_in,
                              void* d_out, int out_size, void* d_ws, size_t ws_size,
                              hipStream_t stream)
{
  const float* x   = (const float*)d_in[0];
  const float* Wq  = (const float*)d_in[1];
  const float* bq  = (const float*)d_in[2];
  const float* Wk  = (const float*)d_in[3];
  const float* bk  = (const float*)d_in[4];
  const float* Wv  = (const float*)d_in[5];
  const float* bv  = (const float*)d_in[6];
  const float* Wo  = (const float*)d_in[7];
  const float* bo  = (const float*)d_in[8];
  const float* W1  = (const float*)d_in[9];
  const float* b1  = (const float*)d_in[10];
  const float* W2  = (const float*)d_in[11];
  const float* b2  = (const float*)d_in[12];
  const float* g1  = (const float*)d_in[13];
  const float* be1 = (const float*)d_in[14];
  const float* g2  = (const float*)d_in[15];
  const float* be2 = (const float*)d_in[16];
  float* out = (float*)d_out;
  char* wsb  = (char*)d_ws;

  const size_t MB = 1ull << 20;
  // byte layout (184 MiB; lifetime-safe overlaps):
  //  [0,16)    xb bf16   (dead after QKV GEMMs)  -> then Cb ctx (dead after Wo)
  //  [16,32)   Qb bf16   (dead after attn)  }
  //  [32,48)   Kb bf16   (dead after attn)  }-- reused as Mh fp32 [16,48)
  //  [48,64)   (unused this round)
  //  [0,64)    F1 bf16   (live from W1 GEMM; everything above dead by then)
  //  [64,80)   VT bf16   (V^T from V-GEMM; dead after attn)
  //  [80,112)  N1 fp32   (live till LN2)
  //  [112,128) N1b bf16  (dead after W1)
  //  [128,160) F2 fp32   (live till LN2)
  //  [160,184) weights: ThQ/K/V/O 2MB each, Th1 8MB, Th2 8MB
  unsigned short* xb  = (unsigned short*)(wsb);
  unsigned short* Cb  = (unsigned short*)(wsb);             // after QKV dead
  unsigned short* Qb  = (unsigned short*)(wsb + 16 * MB);
  unsigned short* Kb  = (unsigned short*)(wsb + 32 * MB);
  unsigned short* F1  = (unsigned short*)(wsb);
  float*          Mh  = (float*)         (wsb + 16 * MB);
  unsigned short* VT  = (unsigned short*)(wsb + 64 * MB);
  float*          N1  = (float*)         (wsb + 80 * MB);
  unsigned short* N1b = (unsigned short*)(wsb + 112 * MB);
  float*          F2  = (float*)         (wsb + 128 * MB);
  unsigned short* ThQ = (unsigned short*)(wsb + 160 * MB);
  unsigned short* ThK = (unsigned short*)(wsb + 162 * MB);
  unsigned short* ThV = (unsigned short*)(wsb + 164 * MB);
  unsigned short* ThO = (unsigned short*)(wsb + 166 * MB);
  unsigned short* Th1 = (unsigned short*)(wsb + 168 * MB);
  unsigned short* Th2 = (unsigned short*)(wsb + 176 * MB);

  dim3 blk(256);
  cvt_bf16_k<<<dim3(NTOK_ * E_ / 1024), blk, 0, stream>>>(x, xb);
  transpose_bf16_k<<<dim3(E_/64,  E_/64),  blk, 0, stream>>>(Wq, ThQ, E_,  E_);
  transpose_bf16_k<<<dim3(E_/64,  E_/64),  blk, 0, stream>>>(Wk, ThK, E_,  E_);
  transpose_bf16_k<<<dim3(E_/64,  E_/64),  blk, 0, stream>>>(Wv, ThV, E_,  E_);
  transpose_bf16_k<<<dim3(E_/64,  E_/64),  blk, 0, stream>>>(Wo, ThO, E_,  E_);
  transpose_bf16_k<<<dim3(FF_/64, E_/64),  blk, 0, stream>>>(W1, Th1, E_,  FF_);
  transpose_bf16_k<<<dim3(E_/64,  FF_/64), blk, 0, stream>>>(W2, Th2, FF_, E_);

  dim3 ge(E_ / 128, NTOK_ / 128);           // (8, 64)   nwg=512  %8==0
  dim3 gf(FF_ / 128, NTOK_ / 128);          // (32, 64)  nwg=2048 %8==0

  gemm_bf16_k<0,1><<<ge, blk, 0, stream>>>(xb,  ThQ, bq, Qb, NTOK_, E_, E_);
  gemm_bf16_k<0,1><<<ge, blk, 0, stream>>>(xb,  ThK, bk, Kb, NTOK_, E_, E_);
  gemm_bf16_k<0,2><<<ge, blk, 0, stream>>>(xb,  ThV, bv, VT, NTOK_, E_, E_);
  attn_mfma_k<<<dim3(S_ / 128, H_, NB_), blk, 0, stream>>>(Qb, Kb, VT, Cb);
  gemm_bf16_k<0,0><<<ge, blk, 0, stream>>>(Cb,  ThO, bo, Mh, NTOK_, E_, E_);
  add_ln_k<1><<<dim3(NTOK_), blk, 0, stream>>>(Mh, x, g1, be1, N1, N1b);
  gemm_bf16_k<1,1><<<gf, blk, 0, stream>>>(N1b, Th1, b1, F1, NTOK_, FF_, E_);
  gemm_bf16_k<0,0><<<ge, blk, 0, stream>>>(F1,  Th2, b2, F2, NTOK_, E_, FF_);
  add_ln_k<0><<<dim3(NTOK_), blk, 0, stream>>>(F2, N1, g2, be2, out, nullptr);
}

// Round 6
// 606.738 us; speedup vs baseline: 1.9860x; 1.2934x over previous
//
#include <hip/hip_runtime.h>
#include <hip/hip_bf16.h>
#include <math.h>

#define E_    1024
#define H_    16
#define DH_   64
#define FF_   4096
#define S_    2048
#define NB_   4
#define NTOK_ 8192   // NB_*S_

typedef float          f32x4_t  __attribute__((ext_vector_type(4)));
typedef unsigned short u16x8_t  __attribute__((ext_vector_type(8)));
typedef unsigned short u16x4_t  __attribute__((ext_vector_type(4)));
typedef __bf16         bf16x8_t __attribute__((ext_vector_type(8)));

#define BC8(x) __builtin_bit_cast(bf16x8_t, (x))

// round-to-nearest-even fp32 -> bf16 (finite inputs)
static __device__ __forceinline__ unsigned short f2bf(float f) {
  unsigned u = __float_as_uint(f);
  return (unsigned short)((u + 0x7FFF + ((u >> 16) & 1)) >> 16);
}

// async global->LDS, 16B per lane. dst is wave-uniform base; HW adds lane*16.
static __device__ __forceinline__ void gl16(const unsigned short* g, unsigned short* l) {
  __builtin_amdgcn_global_load_lds((const __attribute__((address_space(1))) void*)g,
                                   (__attribute__((address_space(3))) void*)l, 16, 0, 0);
}

// ---------------------------------------------------------------------------
// fp32 -> bf16 bulk convert
// ---------------------------------------------------------------------------
__global__ __launch_bounds__(256)
void cvt_bf16_k(const float* __restrict__ in, unsigned short* __restrict__ out)
{
  const size_t i = ((size_t)blockIdx.x * 256 + threadIdx.x) * 4;
  const float4 v = *(const float4*)&in[i];
  u16x4_t p;
  p[0] = f2bf(v.x); p[1] = f2bf(v.y); p[2] = f2bf(v.z); p[3] = f2bf(v.w);
  *(u16x4_t*)&out[i] = p;
}

// ---------------------------------------------------------------------------
// Weight preprocessing: W [K][N] fp32 -> Th [N][K] bf16 (transpose + round).
// ---------------------------------------------------------------------------
__global__ __launch_bounds__(256)
void transpose_bf16_k(const float* __restrict__ W,
                      unsigned short* __restrict__ Th, int K, int N)
{
  __shared__ float tile[64][65];
  const int t  = threadIdx.x;
  const int n0 = blockIdx.x * 64;
  const int k0 = blockIdx.y * 64;
#pragma unroll
  for (int i = 0; i < 4; ++i) {
    const int idx = t + 256 * i;
    const int r  = idx >> 4;
    const int c4 = (idx & 15) * 4;
    const float4 v = *(const float4*)&W[(size_t)(k0 + r) * N + n0 + c4];
    tile[r][c4 + 0] = v.x; tile[r][c4 + 1] = v.y;
    tile[r][c4 + 2] = v.z; tile[r][c4 + 3] = v.w;
  }
  __syncthreads();
#pragma unroll
  for (int i = 0; i < 4; ++i) {
    const int idx = t + 256 * i;
    const int rr  = idx >> 4;
    const int c4  = (idx & 15) * 4;
    u16x4_t hv;
#pragma unroll
    for (int j = 0; j < 4; ++j) hv[j] = f2bf(tile[c4 + j][rr]);
    *(u16x4_t*)&Th[(size_t)(n0 + rr) * K + k0 + c4] = hv;
  }
}

// ---------------------------------------------------------------------------
// bf16 GEMM, m97 structure: global_load_lds(16B) staging, BK=64, linear LDS
// [128][64] with XOR chunk swizzle (source pre-swizzled, reads same-XOR).
// 128x128 tile, 4 waves 2x2, 4x4 frags of 16x16x32_bf16, fp32 accum.
// MODE 0: fp32 row-major  MODE 1: bf16 row-major  MODE 2: bf16 V^T [n][h][d][s]
// ---------------------------------------------------------------------------
template<int RELU, int MODE>
__global__ __launch_bounds__(256)
void gemm_bf16_k(const unsigned short* __restrict__ A,
                 const unsigned short* __restrict__ Th,
                 const float* __restrict__ bias, void* __restrict__ outp,
                 int M, int N, int K)
{
  __shared__ __align__(16) unsigned short As[128][64];
  __shared__ __align__(16) unsigned short Bs[128][64];
  const int t    = threadIdx.x;
  const int nwg  = gridDim.x * gridDim.y;
  int id = blockIdx.x + gridDim.x * blockIdx.y;
  id = (id & 7) * (nwg >> 3) + (id >> 3);       // XCD chunk swizzle (nwg%8==0)
  const int bn = (id % gridDim.x) * 128;
  const int bm = (id / gridDim.x) * 128;
  const int lane = t & 63;
  const int wid  = t >> 6;
  const int wr   = wid >> 1;
  const int wc   = wid & 1;
  const int fr   = lane & 15;
  const int hi   = lane >> 4;

  const int r8  = lane >> 3;            // row within 8-row staging group
  const int csw = (lane & 7) ^ r8;      // inverse-swizzled source chunk

  f32x4_t acc[4][4];
#pragma unroll
  for (int m = 0; m < 4; ++m)
#pragma unroll
    for (int n = 0; n < 4; ++n)
#pragma unroll
      for (int j = 0; j < 4; ++j) acc[m][n][j] = 0.0f;

  const unsigned short* agl = A  + (size_t)(bm + wid * 32 + r8) * K + csw * 8;
  const unsigned short* bgl = Th + (size_t)(bn + wid * 32 + r8) * K + csw * 8;
  unsigned short* al = &As[wid * 32][0];
  unsigned short* bl = &Bs[wid * 32][0];

  for (int k0 = 0; k0 < K; k0 += 64) {
    __syncthreads();   // previous iteration's frag reads done
#pragma unroll
    for (int i = 0; i < 4; ++i) {
      gl16(agl + (size_t)(i * 8) * K + k0, al + i * 512);
      gl16(bgl + (size_t)(i * 8) * K + k0, bl + i * 512);
    }
    __syncthreads();   // vmcnt(0) drained by barrier -> staged data visible
#pragma unroll
    for (int kk = 0; kk < 2; ++kk) {
      u16x8_t aH[4], bH[4];
#pragma unroll
      for (int m = 0; m < 4; ++m)
        aH[m] = *(const u16x8_t*)&As[wr * 64 + m * 16 + fr][(((kk << 2) | hi) ^ (fr & 7)) * 8];
#pragma unroll
      for (int n = 0; n < 4; ++n)
        bH[n] = *(const u16x8_t*)&Bs[wc * 64 + n * 16 + fr][(((kk << 2) | hi) ^ (fr & 7)) * 8];
#pragma unroll
      for (int m = 0; m < 4; ++m)
#pragma unroll
        for (int n = 0; n < 4; ++n)
          acc[m][n] = __builtin_amdgcn_mfma_f32_16x16x32_bf16(BC8(aH[m]), BC8(bH[n]), acc[m][n], 0, 0, 0);
    }
  }

  // epilogue: C/D layout col=lane&15, row=(lane>>4)*4+reg
#pragma unroll
  for (int n = 0; n < 4; ++n) {
    const int col = bn + wc * 64 + n * 16 + fr;
    const float bv = bias[col];
#pragma unroll
    for (int m = 0; m < 4; ++m) {
      const int row0 = bm + wr * 64 + m * 16 + hi * 4;
      if (MODE == 2) {
        const int nb = row0 >> 11;          // S_=2048
        const int s  = row0 & 2047;
        const int hh = col >> 6;            // DH_=64
        const int dd = col & 63;
        u16x4_t pk;
#pragma unroll
        for (int j = 0; j < 4; ++j) pk[j] = f2bf(acc[m][n][j] + bv);
        *(u16x4_t*)&((unsigned short*)outp)[((size_t)((nb * H_ + hh) * DH_ + dd)) * S_ + s] = pk;
      } else {
#pragma unroll
        for (int j = 0; j < 4; ++j) {
          float v = acc[m][n][j] + bv;
          if (RELU) v = fmaxf(v, 0.0f);
          const size_t o = (size_t)(row0 + j) * N + col;
          if (MODE == 0) ((float*)outp)[o] = v;
          else           ((unsigned short*)outp)[o] = f2bf(v);
        }
      }
    }
  }
}

// ---------------------------------------------------------------------------
// MFMA flash attention, SWAPPED QK^T (s = K x Q -> col=q, row=key):
// row-softmax is in-lane (15 ops) + 2 shfls instead of 4-deep shfl trees.
// Q fragments live in registers for the whole kernel (no Q LDS).
// P is wave-private in LDS (rows wid*32..+32) -> no barrier, just lgkmcnt.
// ---------------------------------------------------------------------------
__global__ __launch_bounds__(256)
void attn_mfma_k(const unsigned short* __restrict__ Qg,
                 const unsigned short* __restrict__ Kg,
                 const unsigned short* __restrict__ VTg,
                 unsigned short* __restrict__ Og)
{
  __shared__ __align__(16) unsigned short Ks[64][72];
  __shared__ __align__(16) unsigned short Vt[64][72];   // [d][key]
  __shared__ __align__(16) unsigned short Ps[128][72];  // [q][key]

  const int t = threadIdx.x;
  const int nwg = gridDim.x * gridDim.y * gridDim.z;     // 1024
  int id = blockIdx.x + gridDim.x * (blockIdx.y + gridDim.y * blockIdx.z);
  id = (id & 7) * (nwg >> 3) + (id >> 3);
  const int qt = id & 15;
  const int h  = (id >> 4) & 15;
  const int n  = id >> 8;

  const int lane = t & 63;
  const int wid  = t >> 6;        // wave owns q rows [wid*32, +32)
  const int fr   = lane & 15;
  const int hi   = lane >> 4;     // 0..3
  const size_t baseq = (size_t)n * S_ * E_ + (size_t)h * DH_;
  const size_t basev = (size_t)(n * H_ + h) * DH_ * S_;

  // ---- Q fragments in registers (B-operand: col=q=fr, k=kk*32+hi*8+e) ----
  u16x8_t qv[2][2];
#pragma unroll
  for (int qf = 0; qf < 2; ++qf)
#pragma unroll
    for (int kk = 0; kk < 2; ++kk)
      qv[qf][kk] = *(const u16x8_t*)&Qg[baseq + (size_t)(qt * 128 + wid * 32 + qf * 16 + fr) * E_ + kk * 32 + hi * 8];

  f32x4_t acc[2][4];              // rows=q(m,hi,j), cols=d
  float m_run[2], l_run[2];       // per qf, for q = qf*16+fr (replicated x4 hi)
#pragma unroll
  for (int m = 0; m < 2; ++m) {
    m_run[m] = -INFINITY; l_run[m] = 0.0f;
#pragma unroll
    for (int nn = 0; nn < 4; ++nn)
#pragma unroll
      for (int j = 0; j < 4; ++j) acc[m][nn][j] = 0.0f;
  }

  const float cs = 0.18033688011112042f;  // log2(e) / sqrt(64)

  for (int kt = 0; kt < S_ / 64; ++kt) {
    // ---- prefetch K and V^T tiles to regs ----
    u16x8_t kr[2], vr[2];
#pragma unroll
    for (int i = 0; i < 2; ++i) {
      const int idx = t + 256 * i;      // 0..511
      const int r   = idx >> 3;         // 0..63
      const int c8  = (idx & 7) * 8;
      kr[i] = *(const u16x8_t*)&Kg[baseq + (size_t)(kt * 64 + r) * E_ + c8];
      vr[i] = *(const u16x8_t*)&VTg[basev + (size_t)r * S_ + kt * 64 + c8];
    }
    __syncthreads();   // all waves done reading Ks/Vt of previous tile
#pragma unroll
    for (int i = 0; i < 2; ++i) {
      const int idx = t + 256 * i;
      const int r   = idx >> 3;
      const int c8  = (idx & 7) * 8;
      *(u16x8_t*)&Ks[r][c8] = kr[i];
      *(u16x8_t*)&Vt[r][c8] = vr[i];
    }
    __syncthreads();

    // ---- QK^T swapped: s[kf][qf], A=K (row=key), B=Q (col=q) ----
    f32x4_t s[4][2];
#pragma unroll
    for (int kf = 0; kf < 4; ++kf)
#pragma unroll
      for (int qf = 0; qf < 2; ++qf)
#pragma unroll
        for (int j = 0; j < 4; ++j) s[kf][qf][j] = 0.0f;
#pragma unroll
    for (int kk = 0; kk < 2; ++kk) {
      u16x8_t ak[4];
#pragma unroll
      for (int kf = 0; kf < 4; ++kf)
        ak[kf] = *(const u16x8_t*)&Ks[kf * 16 + fr][kk * 32 + hi * 8];
#pragma unroll
      for (int kf = 0; kf < 4; ++kf)
#pragma unroll
        for (int qf = 0; qf < 2; ++qf)
          s[kf][qf] = __builtin_amdgcn_mfma_f32_16x16x32_bf16(BC8(ak[kf]), BC8(qv[qf][kk]), s[kf][qf], 0, 0, 0);
    }

    // ---- softmax: in-lane reduce over 16 keys + 2 shfls over hi groups ----
    float corrs[2];
#pragma unroll
    for (int qf = 0; qf < 2; ++qf) {
      float pm = s[0][qf][0];
#pragma unroll
      for (int kf = 0; kf < 4; ++kf)
#pragma unroll
        for (int j = 0; j < 4; ++j) pm = fmaxf(pm, s[kf][qf][j]);
      pm *= cs;
      pm = fmaxf(pm, __shfl_xor(pm, 16));
      pm = fmaxf(pm, __shfl_xor(pm, 32));
      const float mn   = fmaxf(m_run[qf], pm);
      const float corr = exp2f(m_run[qf] - mn);   // first tile: exp2(-inf)=0
      float ps = 0.0f;
#pragma unroll
      for (int kf = 0; kf < 4; ++kf)
#pragma unroll
        for (int j = 0; j < 4; ++j) {
          const float pv = exp2f(s[kf][qf][j] * cs - mn);
          Ps[wid * 32 + qf * 16 + fr][kf * 16 + hi * 4 + j] = f2bf(pv);
          ps += pv;
        }
      ps += __shfl_xor(ps, 16);
      ps += __shfl_xor(ps, 32);
      l_run[qf] = l_run[qf] * corr + ps;
      m_run[qf] = mn;
      corrs[qf] = corr;
    }

    // ---- rescale acc: redistribute corr from lane fr'=hi*4+j ----
#pragma unroll
    for (int m = 0; m < 2; ++m)
#pragma unroll
      for (int j = 0; j < 4; ++j) {
        const float ca = __shfl(corrs[m], hi * 20 + j);
#pragma unroll
        for (int nn = 0; nn < 4; ++nn) acc[m][nn][j] *= ca;
      }

    asm volatile("s_waitcnt lgkmcnt(0)" ::: "memory");  // P writes visible (wave-local)

    // ---- PV: A=P (row=q), B=V^T (col=d), k=key ----
#pragma unroll
    for (int kk = 0; kk < 2; ++kk) {
      u16x8_t ap[2], bv[4];
#pragma unroll
      for (int m = 0; m < 2; ++m)
        ap[m] = *(const u16x8_t*)&Ps[wid * 32 + m * 16 + fr][kk * 32 + hi * 8];
#pragma unroll
      for (int nn = 0; nn < 4; ++nn)
        bv[nn] = *(const u16x8_t*)&Vt[nn * 16 + fr][kk * 32 + hi * 8];
#pragma unroll
      for (int m = 0; m < 2; ++m)
#pragma unroll
        for (int nn = 0; nn < 4; ++nn)
          acc[m][nn] = __builtin_amdgcn_mfma_f32_16x16x32_bf16(BC8(ap[m]), BC8(bv[nn]), acc[m][nn], 0, 0, 0);
    }
  }

  // ---- epilogue: fetch l for my C/D rows, divide, store bf16 ----
#pragma unroll
  for (int m = 0; m < 2; ++m)
#pragma unroll
    for (int j = 0; j < 4; ++j) {
      const float inv = 1.0f / __shfl(l_run[m], hi * 20 + j);
      const size_t o = baseq + (size_t)(qt * 128 + wid * 32 + m * 16 + hi * 4 + j) * E_;
#pragma unroll
      for (int nn = 0; nn < 4; ++nn)
        Og[o + nn * 16 + fr] = f2bf(acc[m][nn][j] * inv);
    }
}

// ---------------------------------------------------------------------------
// out = LayerNorm(A + B) * g + be  (fp32 out; optional bf16 secondary out)
// ---------------------------------------------------------------------------
template<int WB16>
__global__ __launch_bounds__(256)
void add_ln_k(const float* __restrict__ A, const float* __restrict__ B,
              const float* __restrict__ g, const float* __restrict__ be,
              float* __restrict__ out, unsigned short* __restrict__ outb)
{
  __shared__ float red[8];
  const int row = blockIdx.x;
  const int t = threadIdx.x;
  const size_t off = (size_t)row * E_ + t * 4;
  const float4 a = *(const float4*)&A[off];
  const float4 b = *(const float4*)&B[off];
  float4 x;
  x.x = a.x + b.x; x.y = a.y + b.y; x.z = a.z + b.z; x.w = a.w + b.w;

  float s = x.x + x.y + x.z + x.w;
  s += __shfl_xor(s, 1);  s += __shfl_xor(s, 2);  s += __shfl_xor(s, 4);
  s += __shfl_xor(s, 8);  s += __shfl_xor(s, 16); s += __shfl_xor(s, 32);
  if ((t & 63) == 0) red[t >> 6] = s;
  __syncthreads();
  const float mu = (red[0] + red[1] + red[2] + red[3]) * (1.0f / E_);

  float4 xc;
  xc.x = x.x - mu; xc.y = x.y - mu; xc.z = x.z - mu; xc.w = x.w - mu;
  float q = xc.x*xc.x + xc.y*xc.y + xc.z*xc.z + xc.w*xc.w;
  q += __shfl_xor(q, 1);  q += __shfl_xor(q, 2);  q += __shfl_xor(q, 4);
  q += __shfl_xor(q, 8);  q += __shfl_xor(q, 16); q += __shfl_xor(q, 32);
  __syncthreads();
  if ((t & 63) == 0) red[4 + (t >> 6)] = q;
  __syncthreads();
  const float var = (red[4] + red[5] + red[6] + red[7]) * (1.0f / E_);
  const float inv = rsqrtf(var + 1e-5f);

  const float4 gg = *(const float4*)&g[t * 4];
  const float4 bb = *(const float4*)&be[t * 4];
  float4 o;
  o.x = xc.x * inv * gg.x + bb.x;
  o.y = xc.y * inv * gg.y + bb.y;
  o.z = xc.z * inv * gg.z + bb.z;
  o.w = xc.w * inv * gg.w + bb.w;
  *(float4*)&out[off] = o;
  if (WB16) {
    u16x4_t p;
    p[0] = f2bf(o.x); p[1] = f2bf(o.y); p[2] = f2bf(o.z); p[3] = f2bf(o.w);
    *(u16x4_t*)&outb[off] = p;
  }
}

// ---------------------------------------------------------------------------
extern "C" void kernel_launch(void* const* d_in, const int* in_sizes, int n_in,
                              void* d_out, int out_size, void* d_ws, size_t ws_size,
                              hipStream_t stream)
{
  const float* x   = (const float*)d_in[0];
  const float* Wq  = (const float*)d_in[1];
  const float* bq  = (const float*)d_in[2];
  const float* Wk  = (const float*)d_in[3];
  const float* bk  = (const float*)d_in[4];
  const float* Wv  = (const float*)d_in[5];
  const float* bv  = (const float*)d_in[6];
  const float* Wo  = (const float*)d_in[7];
  const float* bo  = (const float*)d_in[8];
  const float* W1  = (const float*)d_in[9];
  const float* b1  = (const float*)d_in[10];
  const float* W2  = (const float*)d_in[11];
  const float* b2  = (const float*)d_in[12];
  const float* g1  = (const float*)d_in[13];
  const float* be1 = (const float*)d_in[14];
  const float* g2  = (const float*)d_in[15];
  const float* be2 = (const float*)d_in[16];
  float* out = (float*)d_out;
  char* wsb  = (char*)d_ws;

  const size_t MB = 1ull << 20;
  // byte layout (184 MiB; lifetime-safe overlaps) — unchanged from round 5
  unsigned short* xb  = (unsigned short*)(wsb);
  unsigned short* Cb  = (unsigned short*)(wsb);             // after QKV dead
  unsigned short* Qb  = (unsigned short*)(wsb + 16 * MB);
  unsigned short* Kb  = (unsigned short*)(wsb + 32 * MB);
  unsigned short* F1  = (unsigned short*)(wsb);
  float*          Mh  = (float*)         (wsb + 16 * MB);
  unsigned short* VT  = (unsigned short*)(wsb + 64 * MB);
  float*          N1  = (float*)         (wsb + 80 * MB);
  unsigned short* N1b = (unsigned short*)(wsb + 112 * MB);
  float*          F2  = (float*)         (wsb + 128 * MB);
  unsigned short* ThQ = (unsigned short*)(wsb + 160 * MB);
  unsigned short* ThK = (unsigned short*)(wsb + 162 * MB);
  unsigned short* ThV = (unsigned short*)(wsb + 164 * MB);
  unsigned short* ThO = (unsigned short*)(wsb + 166 * MB);
  unsigned short* Th1 = (unsigned short*)(wsb + 168 * MB);
  unsigned short* Th2 = (unsigned short*)(wsb + 176 * MB);

  dim3 blk(256);
  cvt_bf16_k<<<dim3(NTOK_ * E_ / 1024), blk, 0, stream>>>(x, xb);
  transpose_bf16_k<<<dim3(E_/64,  E_/64),  blk, 0, stream>>>(Wq, ThQ, E_,  E_);
  transpose_bf16_k<<<dim3(E_/64,  E_/64),  blk, 0, stream>>>(Wk, ThK, E_,  E_);
  transpose_bf16_k<<<dim3(E_/64,  E_/64),  blk, 0, stream>>>(Wv, ThV, E_,  E_);
  transpose_bf16_k<<<dim3(E_/64,  E_/64),  blk, 0, stream>>>(Wo, ThO, E_,  E_);
  transpose_bf16_k<<<dim3(FF_/64, E_/64),  blk, 0, stream>>>(W1, Th1, E_,  FF_);
  transpose_bf16_k<<<dim3(E_/64,  FF_/64), blk, 0, stream>>>(W2, Th2, FF_, E_);

  dim3 ge(E_ / 128, NTOK_ / 128);           // (8, 64)   nwg=512  %8==0
  dim3 gf(FF_ / 128, NTOK_ / 128);          // (32, 64)  nwg=2048 %8==0

  gemm_bf16_k<0,1><<<ge, blk, 0, stream>>>(xb,  ThQ, bq, Qb, NTOK_, E_, E_);
  gemm_bf16_k<0,1><<<ge, blk, 0, stream>>>(xb,  ThK, bk, Kb, NTOK_, E_, E_);
  gemm_bf16_k<0,2><<<ge, blk, 0, stream>>>(xb,  ThV, bv, VT, NTOK_, E_, E_);
  attn_mfma_k<<<dim3(S_ / 128, H_, NB_), blk, 0, stream>>>(Qb, Kb, VT, Cb);
  gemm_bf16_k<0,0><<<ge, blk, 0, stream>>>(Cb,  ThO, bo, Mh, NTOK_, E_, E_);
  add_ln_k<1><<<dim3(NTOK_), blk, 0, stream>>>(Mh, x, g1, be1, N1, N1b);
  gemm_bf16_k<1,1><<<gf, blk, 0, stream>>>(N1b, Th1, b1, F1, NTOK_, FF_, E_);
  gemm_bf16_k<0,0><<<ge, blk, 0, stream>>>(F1,  Th2, b2, F2, NTOK_, E_, FF_);
  add_ln_k<0><<<dim3(NTOK_), blk, 0, stream>>>(F2, N1, g2, be2, out, nullptr);
}

// Round 7
// 603.399 us; speedup vs baseline: 1.9970x; 1.0055x over previous
//
#include <hip/hip_runtime.h>
#include <hip/hip_bf16.h>
#include <math.h>

#define E_    1024
#define H_    16
#define DH_   64
#define FF_   4096
#define S_    2048
#define NB_   4
#define NTOK_ 8192   // NB_*S_

typedef float          f32x4_t  __attribute__((ext_vector_type(4)));
typedef unsigned short u16x8_t  __attribute__((ext_vector_type(8)));
typedef unsigned short u16x4_t  __attribute__((ext_vector_type(4)));
typedef __bf16         bf16x8_t __attribute__((ext_vector_type(8)));

#define BC8(x) __builtin_bit_cast(bf16x8_t, (x))

// round-to-nearest-even fp32 -> bf16 (finite inputs)
static __device__ __forceinline__ unsigned short f2bf(float f) {
  unsigned u = __float_as_uint(f);
  return (unsigned short)((u + 0x7FFF + ((u >> 16) & 1)) >> 16);
}

// packed fp32x2 -> bf16x2 (single instruction; no builtin on gfx950)
static __device__ __forceinline__ unsigned cvt_pk_bf16(float a, float b) {
  unsigned r;
  asm("v_cvt_pk_bf16_f32 %0, %1, %2" : "=v"(r) : "v"(a), "v"(b));
  return r;
}

// async global->LDS, 16B per lane. dst is wave-uniform base; HW adds lane*16.
static __device__ __forceinline__ void gl16(const unsigned short* g, unsigned short* l) {
  __builtin_amdgcn_global_load_lds((const __attribute__((address_space(1))) void*)g,
                                   (__attribute__((address_space(3))) void*)l, 16, 0, 0);
}

// ---------------------------------------------------------------------------
// fp32 -> bf16 bulk convert
// ---------------------------------------------------------------------------
__global__ __launch_bounds__(256)
void cvt_bf16_k(const float* __restrict__ in, unsigned short* __restrict__ out)
{
  const size_t i = ((size_t)blockIdx.x * 256 + threadIdx.x) * 4;
  const float4 v = *(const float4*)&in[i];
  u16x4_t p;
  p[0] = f2bf(v.x); p[1] = f2bf(v.y); p[2] = f2bf(v.z); p[3] = f2bf(v.w);
  *(u16x4_t*)&out[i] = p;
}

// ---------------------------------------------------------------------------
// Weight preprocessing: W [K][N] fp32 -> Th [N][K] bf16 (transpose + round).
// ---------------------------------------------------------------------------
__global__ __launch_bounds__(256)
void transpose_bf16_k(const float* __restrict__ W,
                      unsigned short* __restrict__ Th, int K, int N)
{
  __shared__ float tile[64][65];
  const int t  = threadIdx.x;
  const int n0 = blockIdx.x * 64;
  const int k0 = blockIdx.y * 64;
#pragma unroll
  for (int i = 0; i < 4; ++i) {
    const int idx = t + 256 * i;
    const int r  = idx >> 4;
    const int c4 = (idx & 15) * 4;
    const float4 v = *(const float4*)&W[(size_t)(k0 + r) * N + n0 + c4];
    tile[r][c4 + 0] = v.x; tile[r][c4 + 1] = v.y;
    tile[r][c4 + 2] = v.z; tile[r][c4 + 3] = v.w;
  }
  __syncthreads();
#pragma unroll
  for (int i = 0; i < 4; ++i) {
    const int idx = t + 256 * i;
    const int rr  = idx >> 4;
    const int c4  = (idx & 15) * 4;
    u16x4_t hv;
#pragma unroll
    for (int j = 0; j < 4; ++j) hv[j] = f2bf(tile[c4 + j][rr]);
    *(u16x4_t*)&Th[(size_t)(n0 + rr) * K + k0 + c4] = hv;
  }
}

// ---------------------------------------------------------------------------
// bf16 GEMM, m97 structure: global_load_lds(16B), BK=64, XOR chunk swizzle.
// 128x128 tile, 4 waves 2x2, 4x4 frags 16x16x32, fp32 accum.
// MODE 0: fp32 row-major     MODE 1: bf16 row-major
// MODE 3: fused QKV (N=3072): col block 0->Q bf16, 1->K bf16, 2->V^T layout
// ---------------------------------------------------------------------------
template<int RELU, int MODE>
__global__ __launch_bounds__(256)
void gemm_bf16_k(const unsigned short* __restrict__ A,
                 const unsigned short* __restrict__ Th,
                 const float* __restrict__ bias, const float* __restrict__ bias2,
                 const float* __restrict__ bias3,
                 void* __restrict__ outp, void* __restrict__ outp2,
                 void* __restrict__ outp3,
                 int M, int N, int K)
{
  __shared__ __align__(16) unsigned short As[128][64];
  __shared__ __align__(16) unsigned short Bs[128][64];
  const int t    = threadIdx.x;
  const int nwg  = gridDim.x * gridDim.y;
  int id = blockIdx.x + gridDim.x * blockIdx.y;
  id = (id & 7) * (nwg >> 3) + (id >> 3);       // XCD chunk swizzle (nwg%8==0)
  const int bn = (id % gridDim.x) * 128;
  const int bm = (id / gridDim.x) * 128;
  const int lane = t & 63;
  const int wid  = t >> 6;
  const int wr   = wid >> 1;
  const int wc   = wid & 1;
  const int fr   = lane & 15;
  const int hi   = lane >> 4;

  const int r8  = lane >> 3;            // row within 8-row staging group
  const int csw = (lane & 7) ^ r8;      // inverse-swizzled source chunk

  f32x4_t acc[4][4];
#pragma unroll
  for (int m = 0; m < 4; ++m)
#pragma unroll
    for (int n = 0; n < 4; ++n)
#pragma unroll
      for (int j = 0; j < 4; ++j) acc[m][n][j] = 0.0f;

  const unsigned short* agl = A  + (size_t)(bm + wid * 32 + r8) * K + csw * 8;
  const unsigned short* bgl = Th + (size_t)(bn + wid * 32 + r8) * K + csw * 8;
  unsigned short* al = &As[wid * 32][0];
  unsigned short* bl = &Bs[wid * 32][0];

  for (int k0 = 0; k0 < K; k0 += 64) {
    __syncthreads();   // previous iteration's frag reads done
#pragma unroll
    for (int i = 0; i < 4; ++i) {
      gl16(agl + (size_t)(i * 8) * K + k0, al + i * 512);
      gl16(bgl + (size_t)(i * 8) * K + k0, bl + i * 512);
    }
    __syncthreads();   // barrier drains vmcnt -> staged data visible
#pragma unroll
    for (int kk = 0; kk < 2; ++kk) {
      u16x8_t aH[4], bH[4];
#pragma unroll
      for (int m = 0; m < 4; ++m)
        aH[m] = *(const u16x8_t*)&As[wr * 64 + m * 16 + fr][(((kk << 2) | hi) ^ (fr & 7)) * 8];
#pragma unroll
      for (int n = 0; n < 4; ++n)
        bH[n] = *(const u16x8_t*)&Bs[wc * 64 + n * 16 + fr][(((kk << 2) | hi) ^ (fr & 7)) * 8];
#pragma unroll
      for (int m = 0; m < 4; ++m)
#pragma unroll
        for (int n = 0; n < 4; ++n)
          acc[m][n] = __builtin_amdgcn_mfma_f32_16x16x32_bf16(BC8(aH[m]), BC8(bH[n]), acc[m][n], 0, 0, 0);
    }
  }

  // epilogue: C/D layout col=lane&15, row=(lane>>4)*4+reg
#pragma unroll
  for (int n = 0; n < 4; ++n) {
    const int col = bn + wc * 64 + n * 16 + fr;
#pragma unroll
    for (int m = 0; m < 4; ++m) {
      const int row0 = bm + wr * 64 + m * 16 + hi * 4;
      if (MODE == 3) {
        const int sel  = col >> 10;          // 0:Q 1:K 2:V  (uniform per n)
        const int colm = col & 1023;
        const float bv = (sel == 0 ? bias : sel == 1 ? bias2 : bias3)[colm];
        if (sel == 2) {
          // V^T: [n][h][d][s]; 4 consecutive tokens per lane -> u16x4 along s
          const int nb = row0 >> 11;         // S_=2048
          const int s  = row0 & 2047;
          const int hh = colm >> 6;          // DH_=64
          const int dd = colm & 63;
          u16x4_t pk;
#pragma unroll
          for (int j = 0; j < 4; ++j) pk[j] = f2bf(acc[m][n][j] + bv);
          *(u16x4_t*)&((unsigned short*)outp3)[((size_t)((nb * H_ + hh) * DH_ + dd)) * S_ + s] = pk;
        } else {
          unsigned short* dst = (unsigned short*)(sel == 0 ? outp : outp2);
#pragma unroll
          for (int j = 0; j < 4; ++j)
            dst[(size_t)(row0 + j) * 1024 + colm] = f2bf(acc[m][n][j] + bv);
        }
      } else {
        const float bv = bias[col];
#pragma unroll
        for (int j = 0; j < 4; ++j) {
          float v = acc[m][n][j] + bv;
          if (RELU) v = fmaxf(v, 0.0f);
          const size_t o = (size_t)(row0 + j) * N + col;
          if (MODE == 0) ((float*)outp)[o] = v;
          else           ((unsigned short*)outp)[o] = f2bf(v);
        }
      }
    }
  }
}

// ---------------------------------------------------------------------------
// MFMA flash attention, swapped QK^T + defer-max + cvt_pk packed P.
// Block = (n, h, 128 q-rows), 4 waves x 32 q-rows, K-tiles of 64 keys.
// ---------------------------------------------------------------------------
__global__ __launch_bounds__(256)
void attn_mfma_k(const unsigned short* __restrict__ Qg,
                 const unsigned short* __restrict__ Kg,
                 const unsigned short* __restrict__ VTg,
                 unsigned short* __restrict__ Og)
{
  __shared__ __align__(16) unsigned short Ks[64][72];
  __shared__ __align__(16) unsigned short Vt[64][72];   // [d][key]
  __shared__ __align__(16) unsigned short Ps[128][72];  // [q][key]

  const int t = threadIdx.x;
  const int nwg = gridDim.x * gridDim.y * gridDim.z;     // 1024
  int id = blockIdx.x + gridDim.x * (blockIdx.y + gridDim.y * blockIdx.z);
  id = (id & 7) * (nwg >> 3) + (id >> 3);
  const int qt = id & 15;
  const int h  = (id >> 4) & 15;
  const int n  = id >> 8;

  const int lane = t & 63;
  const int wid  = t >> 6;        // wave owns q rows [wid*32, +32)
  const int fr   = lane & 15;
  const int hi   = lane >> 4;     // 0..3
  const size_t baseq = (size_t)n * S_ * E_ + (size_t)h * DH_;
  const size_t basev = (size_t)(n * H_ + h) * DH_ * S_;

  // ---- Q fragments in registers (B-operand: col=q=fr, k=kk*32+hi*8+e) ----
  u16x8_t qv[2][2];
#pragma unroll
  for (int qf = 0; qf < 2; ++qf)
#pragma unroll
    for (int kk = 0; kk < 2; ++kk)
      qv[qf][kk] = *(const u16x8_t*)&Qg[baseq + (size_t)(qt * 128 + wid * 32 + qf * 16 + fr) * E_ + kk * 32 + hi * 8];

  f32x4_t acc[2][4];              // rows=q(hi,j), cols=d
  float m_run[2], l_run[2];       // per qf, for q = qf*16+fr (replicated x4 hi)
#pragma unroll
  for (int m = 0; m < 2; ++m) {
    m_run[m] = -INFINITY; l_run[m] = 0.0f;
#pragma unroll
    for (int nn = 0; nn < 4; ++nn)
#pragma unroll
      for (int j = 0; j < 4; ++j) acc[m][nn][j] = 0.0f;
  }

  const float cs = 0.18033688011112042f;  // log2(e) / sqrt(64)

  for (int kt = 0; kt < S_ / 64; ++kt) {
    // ---- prefetch K and V^T tiles to regs ----
    u16x8_t kr[2], vr[2];
#pragma unroll
    for (int i = 0; i < 2; ++i) {
      const int idx = t + 256 * i;      // 0..511
      const int r   = idx >> 3;         // 0..63
      const int c8  = (idx & 7) * 8;
      kr[i] = *(const u16x8_t*)&Kg[baseq + (size_t)(kt * 64 + r) * E_ + c8];
      vr[i] = *(const u16x8_t*)&VTg[basev + (size_t)r * S_ + kt * 64 + c8];
    }
    __syncthreads();   // all waves done reading Ks/Vt of previous tile
#pragma unroll
    for (int i = 0; i < 2; ++i) {
      const int idx = t + 256 * i;
      const int r   = idx >> 3;
      const int c8  = (idx & 7) * 8;
      *(u16x8_t*)&Ks[r][c8] = kr[i];
      *(u16x8_t*)&Vt[r][c8] = vr[i];
    }
    __syncthreads();

    // ---- QK^T swapped: s[kf][qf], A=K (row=key), B=Q (col=q) ----
    f32x4_t s[4][2];
#pragma unroll
    for (int kf = 0; kf < 4; ++kf)
#pragma unroll
      for (int qf = 0; qf < 2; ++qf)
#pragma unroll
        for (int j = 0; j < 4; ++j) s[kf][qf][j] = 0.0f;
#pragma unroll
    for (int kk = 0; kk < 2; ++kk) {
      u16x8_t ak[4];
#pragma unroll
      for (int kf = 0; kf < 4; ++kf)
        ak[kf] = *(const u16x8_t*)&Ks[kf * 16 + fr][kk * 32 + hi * 8];
#pragma unroll
      for (int kf = 0; kf < 4; ++kf)
#pragma unroll
        for (int qf = 0; qf < 2; ++qf)
          s[kf][qf] = __builtin_amdgcn_mfma_f32_16x16x32_bf16(BC8(ak[kf]), BC8(qv[qf][kk]), s[kf][qf], 0, 0, 0);
    }

    // ---- in-lane partial max (16 keys of this lane's row slice) ----
    float pml[2];
#pragma unroll
    for (int qf = 0; qf < 2; ++qf) {
      const float a0 = fmaxf(fmaxf(s[0][qf][0], s[0][qf][1]), fmaxf(s[0][qf][2], s[0][qf][3]));
      const float a1 = fmaxf(fmaxf(s[1][qf][0], s[1][qf][1]), fmaxf(s[1][qf][2], s[1][qf][3]));
      const float a2 = fmaxf(fmaxf(s[2][qf][0], s[2][qf][1]), fmaxf(s[2][qf][2], s[2][qf][3]));
      const float a3 = fmaxf(fmaxf(s[3][qf][0], s[3][qf][1]), fmaxf(s[3][qf][2], s[3][qf][3]));
      pml[qf] = fmaxf(fmaxf(a0, a1), fmaxf(a2, a3)) * cs;
    }

    // ---- defer-max: full rescale only when some row grew past m_old+8 ----
    // (__any over 64 lanes covers every slice of every row in the wave)
    const bool need = (pml[0] > m_run[0] + 8.f) || (pml[1] > m_run[1] + 8.f);
    if (__any(need ? 1 : 0)) {
      float corr[2];
#pragma unroll
      for (int qf = 0; qf < 2; ++qf) {
        float pm = pml[qf];
        pm = fmaxf(pm, __shfl_xor(pm, 16));
        pm = fmaxf(pm, __shfl_xor(pm, 32));
        const float mn = fmaxf(m_run[qf], pm);
        corr[qf] = exp2f(m_run[qf] - mn);   // first tile: exp2(-inf)=0
        m_run[qf] = mn;
        l_run[qf] *= corr[qf];
      }
#pragma unroll
      for (int m = 0; m < 2; ++m)
#pragma unroll
        for (int j = 0; j < 4; ++j) {
          const float ca = __shfl(corr[m], hi * 20 + j);
#pragma unroll
          for (int nn = 0; nn < 4; ++nn) acc[m][nn][j] *= ca;
        }
    }

    // ---- P = exp2(s*cs - m), packed bf16 pairs, b64 LDS writes ----
#pragma unroll
    for (int qf = 0; qf < 2; ++qf) {
      const int prow = wid * 32 + qf * 16 + fr;
      float ps = 0.0f;
#pragma unroll
      for (int kf = 0; kf < 4; ++kf) {
        const float p0 = exp2f(__builtin_fmaf(s[kf][qf][0], cs, -m_run[qf]));
        const float p1 = exp2f(__builtin_fmaf(s[kf][qf][1], cs, -m_run[qf]));
        const float p2 = exp2f(__builtin_fmaf(s[kf][qf][2], cs, -m_run[qf]));
        const float p3 = exp2f(__builtin_fmaf(s[kf][qf][3], cs, -m_run[qf]));
        ps += (p0 + p1) + (p2 + p3);
        uint2 w;
        w.x = cvt_pk_bf16(p0, p1);
        w.y = cvt_pk_bf16(p2, p3);
        *(uint2*)&Ps[prow][kf * 16 + hi * 4] = w;
      }
      ps += __shfl_xor(ps, 16);
      ps += __shfl_xor(ps, 32);
      l_run[qf] += ps;
    }

    asm volatile("s_waitcnt lgkmcnt(0)" ::: "memory");  // wave-local P visible

    // ---- PV: A=P (row=q), B=V^T (col=d), k=key ----
#pragma unroll
    for (int kk = 0; kk < 2; ++kk) {
      u16x8_t ap[2], bv[4];
#pragma unroll
      for (int m = 0; m < 2; ++m)
        ap[m] = *(const u16x8_t*)&Ps[wid * 32 + m * 16 + fr][kk * 32 + hi * 8];
#pragma unroll
      for (int nn = 0; nn < 4; ++nn)
        bv[nn] = *(const u16x8_t*)&Vt[nn * 16 + fr][kk * 32 + hi * 8];
#pragma unroll
      for (int m = 0; m < 2; ++m)
#pragma unroll
        for (int nn = 0; nn < 4; ++nn)
          acc[m][nn] = __builtin_amdgcn_mfma_f32_16x16x32_bf16(BC8(ap[m]), BC8(bv[nn]), acc[m][nn], 0, 0, 0);
    }
  }

  // ---- epilogue: fetch l for my C/D rows, divide, store bf16 ----
#pragma unroll
  for (int m = 0; m < 2; ++m)
#pragma unroll
    for (int j = 0; j < 4; ++j) {
      const float inv = 1.0f / __shfl(l_run[m], hi * 20 + j);
      const size_t o = baseq + (size_t)(qt * 128 + wid * 32 + m * 16 + hi * 4 + j) * E_;
#pragma unroll
      for (int nn = 0; nn < 4; ++nn)
        Og[o + nn * 16 + fr] = f2bf(acc[m][nn][j] * inv);
    }
}

// ---------------------------------------------------------------------------
// out = LayerNorm(A + B) * g + be  (fp32 out; optional bf16 secondary out)
// ---------------------------------------------------------------------------
template<int WB16>
__global__ __launch_bounds__(256)
void add_ln_k(const float* __restrict__ A, const float* __restrict__ B,
              const float* __restrict__ g, const float* __restrict__ be,
              float* __restrict__ out, unsigned short* __restrict__ outb)
{
  __shared__ float red[8];
  const int row = blockIdx.x;
  const int t = threadIdx.x;
  const size_t off = (size_t)row * E_ + t * 4;
  const float4 a = *(const float4*)&A[off];
  const float4 b = *(const float4*)&B[off];
  float4 x;
  x.x = a.x + b.x; x.y = a.y + b.y; x.z = a.z + b.z; x.w = a.w + b.w;

  float s = x.x + x.y + x.z + x.w;
  s += __shfl_xor(s, 1);  s += __shfl_xor(s, 2);  s += __shfl_xor(s, 4);
  s += __shfl_xor(s, 8);  s += __shfl_xor(s, 16); s += __shfl_xor(s, 32);
  if ((t & 63) == 0) red[t >> 6] = s;
  __syncthreads();
  const float mu = (red[0] + red[1] + red[2] + red[3]) * (1.0f / E_);

  float4 xc;
  xc.x = x.x - mu; xc.y = x.y - mu; xc.z = x.z - mu; xc.w = x.w - mu;
  float q = xc.x*xc.x + xc.y*xc.y + xc.z*xc.z + xc.w*xc.w;
  q += __shfl_xor(q, 1);  q += __shfl_xor(q, 2);  q += __shfl_xor(q, 4);
  q += __shfl_xor(q, 8);  q += __shfl_xor(q, 16); q += __shfl_xor(q, 32);
  __syncthreads();
  if ((t & 63) == 0) red[4 + (t >> 6)] = q;
  __syncthreads();
  const float var = (red[4] + red[5] + red[6] + red[7]) * (1.0f / E_);
  const float inv = rsqrtf(var + 1e-5f);

  const float4 gg = *(const float4*)&g[t * 4];
  const float4 bb = *(const float4*)&be[t * 4];
  float4 o;
  o.x = xc.x * inv * gg.x + bb.x;
  o.y = xc.y * inv * gg.y + bb.y;
  o.z = xc.z * inv * gg.z + bb.z;
  o.w = xc.w * inv * gg.w + bb.w;
  *(float4*)&out[off] = o;
  if (WB16) {
    u16x4_t p;
    p[0] = f2bf(o.x); p[1] = f2bf(o.y); p[2] = f2bf(o.z); p[3] = f2bf(o.w);
    *(u16x4_t*)&outb[off] = p;
  }
}

// ---------------------------------------------------------------------------
extern "C" void kernel_launch(void* const* d_in, const int* in_sizes, int n_in,
                              void* d_out, int out_size, void* d_ws, size_t ws_size,
                              hipStream_t stream)
{
  const float* x   = (const float*)d_in[0];
  const float* Wq  = (const float*)d_in[1];
  const float* bq  = (const float*)d_in[2];
  const float* Wk  = (const float*)d_in[3];
  const float* bk  = (const float*)d_in[4];
  const float* Wv  = (const float*)d_in[5];
  const float* bv  = (const float*)d_in[6];
  const float* Wo  = (const float*)d_in[7];
  const float* bo  = (const float*)d_in[8];
  const float* W1  = (const float*)d_in[9];
  const float* b1  = (const float*)d_in[10];
  const float* W2  = (const float*)d_in[11];
  const float* b2  = (const float*)d_in[12];
  const float* g1  = (const float*)d_in[13];
  const float* be1 = (const float*)d_in[14];
  const float* g2  = (const float*)d_in[15];
  const float* be2 = (const float*)d_in[16];
  float* out = (float*)d_out;
  char* wsb  = (char*)d_ws;

  const size_t MB = 1ull << 20;
  // byte layout (184 MiB; lifetime-safe overlaps):
  //  [0,16)    xb bf16   (dead after QKV)  -> then Cb ctx (dead after Wo)
  //  [16,32)   Qb bf16   (dead after attn) }
  //  [32,48)   Kb bf16   (dead after attn) }-- reused as Mh fp32 [16,48)
  //  [0,64)    F1 bf16   (live from W1 GEMM; everything above dead by then)
  //  [64,80)   VT bf16   (V^T from fused QKV; dead after attn)
  //  [80,112)  N1 fp32   (live till LN2)
  //  [112,128) N1b bf16  (dead after W1)
  //  [128,160) F2 fp32   (live till LN2)
  //  [160,184) weights: ThQKV 6MB, ThO 2MB, Th1 8MB, Th2 8MB
  unsigned short* xb  = (unsigned short*)(wsb);
  unsigned short* Cb  = (unsigned short*)(wsb);             // after QKV dead
  unsigned short* Qb  = (unsigned short*)(wsb + 16 * MB);
  unsigned short* Kb  = (unsigned short*)(wsb + 32 * MB);
  unsigned short* F1  = (unsigned short*)(wsb);
  float*          Mh  = (float*)         (wsb + 16 * MB);
  unsigned short* VT  = (unsigned short*)(wsb + 64 * MB);
  float*          N1  = (float*)         (wsb + 80 * MB);
  unsigned short* N1b = (unsigned short*)(wsb + 112 * MB);
  float*          F2  = (float*)         (wsb + 128 * MB);
  unsigned short* ThQKV = (unsigned short*)(wsb + 160 * MB);
  const size_t EE = (size_t)E_ * E_;
  unsigned short* ThO = (unsigned short*)(wsb + 166 * MB);
  unsigned short* Th1 = (unsigned short*)(wsb + 168 * MB);
  unsigned short* Th2 = (unsigned short*)(wsb + 176 * MB);

  dim3 blk(256);
  cvt_bf16_k<<<dim3(NTOK_ * E_ / 1024), blk, 0, stream>>>(x, xb);
  transpose_bf16_k<<<dim3(E_/64,  E_/64),  blk, 0, stream>>>(Wq, ThQKV,          E_,  E_);
  transpose_bf16_k<<<dim3(E_/64,  E_/64),  blk, 0, stream>>>(Wk, ThQKV + EE,     E_,  E_);
  transpose_bf16_k<<<dim3(E_/64,  E_/64),  blk, 0, stream>>>(Wv, ThQKV + 2 * EE, E_,  E_);
  transpose_bf16_k<<<dim3(E_/64,  E_/64),  blk, 0, stream>>>(Wo, ThO, E_,  E_);
  transpose_bf16_k<<<dim3(FF_/64, E_/64),  blk, 0, stream>>>(W1, Th1, E_,  FF_);
  transpose_bf16_k<<<dim3(E_/64,  FF_/64), blk, 0, stream>>>(W2, Th2, FF_, E_);

  dim3 ge (E_ / 128,      NTOK_ / 128);     // (8, 64)   nwg=512  %8==0
  dim3 ge3(3 * E_ / 128,  NTOK_ / 128);     // (24, 64)  nwg=1536 %8==0
  dim3 gf (FF_ / 128,     NTOK_ / 128);     // (32, 64)  nwg=2048 %8==0

  gemm_bf16_k<0,3><<<ge3, blk, 0, stream>>>(xb, ThQKV, bq, bk, bv, Qb, Kb, VT, NTOK_, 3 * E_, E_);
  attn_mfma_k<<<dim3(S_ / 128, H_, NB_), blk, 0, stream>>>(Qb, Kb, VT, Cb);
  gemm_bf16_k<0,0><<<ge, blk, 0, stream>>>(Cb, ThO, bo, nullptr, nullptr, Mh, nullptr, nullptr, NTOK_, E_, E_);
  add_ln_k<1><<<dim3(NTOK_), blk, 0, stream>>>(Mh, x, g1, be1, N1, N1b);
  gemm_bf16_k<1,1><<<gf, blk, 0, stream>>>(N1b, Th1, b1, nullptr, nullptr, F1, nullptr, nullptr, NTOK_, FF_, E_);
  gemm_bf16_k<0,0><<<ge, blk, 0, stream>>>(F1, Th2, b2, nullptr, nullptr, F2, nullptr, nullptr, NTOK_, E_, FF_);
  add_ln_k<0><<<dim3(NTOK_), blk, 0, stream>>>(F2, N1, g2, be2, out, nullptr);
}